// Round 1
// baseline (769.542 us; speedup 1.0000x reference)
//
#include <hip/hip_runtime.h>
#include <stdint.h>
#include <stddef.h>

#define NB 8
#define CC 192
#define C3 576
#define HGT 128
#define WID 128
#define HW 16384
#define NH 8

typedef short bf16x8 __attribute__((ext_vector_type(8)));
typedef float f32x4 __attribute__((ext_vector_type(4)));

__device__ __forceinline__ unsigned short f2bf(float f) {
  unsigned int u = __float_as_uint(f);
  u += 0x7fffu + ((u >> 16) & 1u);
  return (unsigned short)(u >> 16);
}
__device__ __forceinline__ float bf2f(unsigned short h) {
  return __uint_as_float(((unsigned int)h) << 16);
}
__device__ __forceinline__ void gl_lds16(const void* g, void* l) {
  __builtin_amdgcn_global_load_lds(
      (const __attribute__((address_space(1))) unsigned int*)(uintptr_t)g,
      (__attribute__((address_space(3))) unsigned int*)(uint32_t)(uintptr_t)l,
      16, 0, 0);
}
__device__ __forceinline__ int xcd_swz(int g, int n) {
  return (g & 7) * (n >> 3) + (g >> 3);
}

// ---------------- ktrans: x [b][192][HW] f32 -> xT [b][p][192] bf16, rows XOR-swizzled
__global__ __launch_bounds__(256) void ktrans(const float* __restrict__ x,
                                              unsigned short* __restrict__ xT) {
  __shared__ __align__(16) float lx[192 * 68];
  int wg = xcd_swz(blockIdx.x, gridDim.x);
  int pt = wg & 255, b = wg >> 8;
  int p0 = pt * 64;
  int tid = threadIdx.x;
#pragma unroll
  for (int i = 0; i < 12; ++i) {
    int f = tid + i * 256;
    int ic = f >> 4, q = f & 15;
    float4 v = *(const float4*)(x + ((size_t)(b * CC + ic)) * HW + p0 + q * 4);
    *(float4*)(lx + ic * 68 + q * 4) = v;
  }
  __syncthreads();
  int p = tid & 63, sg = tid >> 6;
  unsigned char* row = (unsigned char*)xT + ((size_t)b * HW + p0 + p) * 384;
  int key = p & 7;
#pragma unroll
  for (int s6 = 0; s6 < 6; ++s6) {
    int s = sg * 6 + s6;
    unsigned int wv[4];
#pragma unroll
    for (int j = 0; j < 4; ++j) {
      float f0 = lx[(s * 8 + 2 * j) * 68 + p];
      float f1 = lx[(s * 8 + 2 * j + 1) * 68 + p];
      wv[j] = (unsigned int)f2bf(f0) | ((unsigned int)f2bf(f1) << 16);
    }
    uint4 st; st.x = wv[0]; st.y = wv[1]; st.z = wv[2]; st.w = wv[3];
    *(uint4*)(row + ((s ^ key) * 16)) = st;
  }
}

// ---------------- kwprep: w_qkv [576][192] f32 -> bf16 swizzled rows
__global__ void kwprep(const float* __restrict__ wq, unsigned char* __restrict__ wb) {
  int f = blockIdx.x * 256 + threadIdx.x;
  if (f >= C3 * 24) return;
  int oc = f / 24, s = f % 24;
  unsigned int wv[4];
#pragma unroll
  for (int j = 0; j < 4; ++j) {
    float f0 = wq[oc * 192 + s * 8 + 2 * j];
    float f1 = wq[oc * 192 + s * 8 + 2 * j + 1];
    wv[j] = (unsigned int)f2bf(f0) | ((unsigned int)f2bf(f1) << 16);
  }
  uint4 st; st.x = wv[0]; st.y = wv[1]; st.z = wv[2]; st.w = wv[3];
  *(uint4*)(wb + (size_t)oc * 384 + ((s ^ (oc & 7)) * 16)) = st;
}

// ---------------- kconv1: t[b][oc][p] = sum_ic w[oc][ic]*x[ic][p] + bqkv  (bf16 MFMA)
__global__ __launch_bounds__(256) void kconv1(const unsigned char* __restrict__ xT,
                                              const unsigned char* __restrict__ wb,
                                              const float* __restrict__ bqkv,
                                              unsigned short* __restrict__ t) {
  __shared__ __align__(16) unsigned char lds[73728]; // A:49152  B:24576
  int wg = xcd_swz(blockIdx.x, gridDim.x);
  int ot = wg % 9;
  int pt = (wg / 9) & 127;
  int b = wg / 1152;
  int tid = threadIdx.x;
  const unsigned char* gA = xT + ((size_t)b * HW + pt * 128) * 384;
  const unsigned char* gB = wb + (size_t)ot * 64 * 384;
#pragma unroll
  for (int i = 0; i < 12; ++i)
    gl_lds16(gA + i * 4096 + tid * 16, lds + i * 4096 + tid * 16);
#pragma unroll
  for (int i = 0; i < 6; ++i)
    gl_lds16(gB + i * 4096 + tid * 16, lds + 49152 + i * 4096 + tid * 16);
  asm volatile("s_waitcnt vmcnt(0)" ::: "memory");
  __syncthreads();

  int lane = tid & 63, wv = tid >> 6;
  int l15 = lane & 15, gq = lane >> 4;
  int pw = (wv >> 1) * 64, ow = (wv & 1) * 32;
  f32x4 acc[4][2];
#pragma unroll
  for (int a = 0; a < 4; ++a)
#pragma unroll
    for (int c = 0; c < 2; ++c) acc[a][c] = (f32x4){0.f, 0.f, 0.f, 0.f};

#pragma unroll
  for (int kk = 0; kk < 6; ++kk) {
    int cb = kk * 64 + gq * 16;
    bf16x8 af[4], bfr[2];
#pragma unroll
    for (int mf = 0; mf < 4; ++mf) {
      int r = pw + mf * 16 + l15;
      af[mf] = *(const bf16x8*)(lds + r * 384 + (cb ^ ((r & 7) << 4)));
    }
#pragma unroll
    for (int nf = 0; nf < 2; ++nf) {
      int r = ow + nf * 16 + l15;
      bfr[nf] = *(const bf16x8*)(lds + 49152 + r * 384 + (cb ^ ((r & 7) << 4)));
    }
#pragma unroll
    for (int mf = 0; mf < 4; ++mf)
#pragma unroll
      for (int nf = 0; nf < 2; ++nf)
        acc[mf][nf] = __builtin_amdgcn_mfma_f32_16x16x32_bf16(af[mf], bfr[nf], acc[mf][nf], 0, 0, 0);
  }
#pragma unroll
  for (int nf = 0; nf < 2; ++nf) {
    int oc = ot * 64 + ow + nf * 16 + l15;
    float bias = bqkv[oc];
    size_t rowb = ((size_t)b * C3 + oc) * HW;
#pragma unroll
    for (int mf = 0; mf < 4; ++mf) {
      int p = pt * 128 + pw + mf * 16 + gq * 4;
      unsigned int lo = (unsigned int)f2bf(acc[mf][nf][0] + bias) |
                        ((unsigned int)f2bf(acc[mf][nf][1] + bias) << 16);
      unsigned int hi = (unsigned int)f2bf(acc[mf][nf][2] + bias) |
                        ((unsigned int)f2bf(acc[mf][nf][3] + bias) << 16);
      uint2 st; st.x = lo; st.y = hi;
      *(uint2*)(t + rowb + p) = st;
    }
  }
}

// ---------------- kdw: depthwise conv on t; writes vT (bf16 swz), Gram G, sq-norms
__global__ __launch_bounds__(256) void kdw(const unsigned short* __restrict__ t,
                                           const float* __restrict__ wdw,
                                           const float* __restrict__ bdw,
                                           unsigned char* __restrict__ vT,
                                           float* __restrict__ G,
                                           float* __restrict__ nq,
                                           float* __restrict__ nk) {
  __shared__ unsigned short bufT[8640];                 // 24ch x 18r x 20 cols
  __shared__ __align__(16) unsigned char qlds[16384];   // 32 x 256 bf16 (swz)
  __shared__ __align__(16) unsigned char klds[16384];
  int wg = xcd_swz(blockIdx.x, gridDim.x);
  int h = wg & 7, tile = (wg >> 3) & 63, b = wg >> 9;
  int y0 = (tile >> 3) * 16, x0 = (tile & 7) * 16;
  int tid = threadIdx.x;
  int py = tid >> 4, pxx = tid & 15;
  {
    unsigned int* q32 = (unsigned int*)(qlds + 12288);
    unsigned int* k32 = (unsigned int*)(klds + 12288);
    for (int i = tid; i < 1024; i += 256) { q32[i] = 0; k32[i] = 0; }
  }
  unsigned int vpack[12];
#pragma unroll
  for (int pass = 0; pass < 3; ++pass) {
    int part = (pass == 0) ? 2 : (pass - 1);   // v, q, k
    int chg0 = part * 192 + h * 24;
    __syncthreads();
#pragma unroll
    for (int i = 0; i < 17; ++i) {
      int f = tid + i * 256;
      if (f < 4320) {
        int ch = f / 180, rr = f % 180;
        int r = rr / 10, d = rr % 10;
        int yy = y0 + r - 1, xx = x0 + d * 2 - 2;
        unsigned int val = 0;
        if (yy >= 0 && yy < HGT && xx >= 0 && xx < WID)
          val = *(const unsigned int*)(t + ((size_t)(b * C3 + chg0 + ch)) * HW + yy * WID + xx);
        *(unsigned int*)((unsigned char*)bufT + (size_t)(ch * 720 + r * 40 + d * 4)) = val;
      }
    }
    __syncthreads();
#pragma unroll
    for (int ch = 0; ch < 24; ++ch) {
      int chg = chg0 + ch;
      const float* wv = wdw + chg * 9;
      float acc = bdw[chg];
#pragma unroll
      for (int dy = 0; dy < 3; ++dy)
#pragma unroll
        for (int dx = 0; dx < 3; ++dx)
          acc += bf2f(bufT[ch * 360 + (py + dy) * 20 + pxx + dx + 1]) * wv[dy * 3 + dx];
      unsigned short hb = f2bf(acc);
      if (pass == 0) {
        if (ch & 1) vpack[ch >> 1] |= ((unsigned int)hb << 16);
        else vpack[ch >> 1] = hb;
      } else {
        unsigned char* dst = (pass == 1) ? qlds : klds;
        *(unsigned short*)(dst + ch * 512 + ((tid * 2) ^ ((ch & 7) << 4))) = hb;
      }
    }
    if (pass == 0) {
      int p = (y0 + py) * WID + x0 + pxx;
      unsigned char* row = vT + ((size_t)b * HW + p) * 384;
      int key = p & 7;
#pragma unroll
      for (int s = 0; s < 3; ++s) {
        uint4 st;
        st.x = vpack[s * 4 + 0]; st.y = vpack[s * 4 + 1];
        st.z = vpack[s * 4 + 2]; st.w = vpack[s * 4 + 3];
        *(uint4*)(row + (((3 * h + s) ^ key) * 16)) = st;
      }
    }
  }
  __syncthreads();
  if (tid < 64) {  // Gram via MFMA on wave 0
    int l15 = tid & 15, gq = tid >> 4;
#pragma unroll
    for (int ct = 0; ct < 2; ++ct)
#pragma unroll
      for (int dt = 0; dt < 2; ++dt) {
        f32x4 acc = (f32x4){0.f, 0.f, 0.f, 0.f};
        int rq = ct * 16 + l15, rk = dt * 16 + l15;
#pragma unroll
        for (int kk = 0; kk < 8; ++kk) {
          int cb = kk * 64 + gq * 16;
          bf16x8 a = *(const bf16x8*)(qlds + rq * 512 + (cb ^ ((rq & 7) << 4)));
          bf16x8 bb = *(const bf16x8*)(klds + rk * 512 + (cb ^ ((rk & 7) << 4)));
          acc = __builtin_amdgcn_mfma_f32_16x16x32_bf16(a, bb, acc, 0, 0, 0);
        }
#pragma unroll
        for (int r = 0; r < 4; ++r) {
          int c = ct * 16 + gq * 4 + r, d = dt * 16 + l15;
          if (c < 24 && d < 24)
            atomicAdd(&G[(((size_t)b * NH + h) * 24 + c) * 24 + d], acc[r]);
        }
      }
  } else {        // squared norms on threads 64..255
    int idx = tid - 64;
    int c48 = idx >> 2, quarter = idx & 3;
    int c = (c48 < 24) ? c48 : (c48 - 24);
    const unsigned char* src = (c48 < 24) ? qlds : klds;
    float s = 0.f;
    int pb = quarter * 64;
#pragma unroll
    for (int p2 = 0; p2 < 64; ++p2) {
      int px2 = pb + p2;
      float v = bf2f(*(const unsigned short*)(src + c * 512 + ((px2 * 2) ^ ((c & 7) << 4))));
      s += v * v;
    }
    float* dstn = (c48 < 24) ? nq : nk;
    atomicAdd(&dstn[((size_t)b * NH + h) * 24 + c], s);
  }
}

// ---------------- kattn: softmax + fold w_proj -> W2[b] (bf16 swz rows)
__global__ __launch_bounds__(256) void kattn(const float* __restrict__ G,
                                             const float* __restrict__ nq,
                                             const float* __restrict__ nk,
                                             const float* __restrict__ temp,
                                             const float* __restrict__ wproj,
                                             unsigned char* __restrict__ W2) {
  __shared__ float attn[24][24];
  __shared__ float iq[24], ik[24];
  int bh = blockIdx.x;
  int h = bh & 7, b = bh >> 3;
  int tid = threadIdx.x;
  const float* Gb = G + (size_t)bh * 576;
  if (tid < 24) { float n = sqrtf(nq[bh * 24 + tid]); iq[tid] = 1.f / fmaxf(n, 1e-12f); }
  else if (tid < 48) { float n = sqrtf(nk[bh * 24 + tid - 24]); ik[tid - 24] = 1.f / fmaxf(n, 1e-12f); }
  __syncthreads();
  if (tid < 24) {
    float tmp = temp[h];
    float row[24];
    float mx = -1e30f;
#pragma unroll
    for (int d = 0; d < 24; ++d) {
      row[d] = Gb[tid * 24 + d] * iq[tid] * ik[d] * tmp;
      mx = fmaxf(mx, row[d]);
    }
    float sum = 0.f;
#pragma unroll
    for (int d = 0; d < 24; ++d) { float e = expf(row[d] - mx); row[d] = e; sum += e; }
    float inv = 1.f / sum;
#pragma unroll
    for (int d = 0; d < 24; ++d) attn[tid][d] = row[d] * inv;
  }
  __syncthreads();
  for (int i = 0; i < 18; ++i) {
    int f = tid + i * 256;
    if (f >= 4608) break;
    int oc = f / 24, d = f % 24;
    float s = 0.f;
#pragma unroll
    for (int c = 0; c < 24; ++c) s += wproj[oc * 192 + h * 24 + c] * attn[c][d];
    int gg = h * 24 + d;
    *(unsigned short*)(W2 + ((size_t)b * CC + oc) * 384 + ((gg * 2) ^ ((oc & 7) << 4))) = f2bf(s);
  }
}

// ---------------- kpos: pos = dwconv(gelu(dwconv(v,w1)),w2), bf16 [b][oc][p]
__global__ __launch_bounds__(256) void kpos(const unsigned char* __restrict__ vT,
                                            const float* __restrict__ w1,
                                            const float* __restrict__ w2,
                                            unsigned short* __restrict__ pos) {
  __shared__ unsigned short vb[24 * 6 * 132];
  __shared__ unsigned short d1[24 * 4 * 130];
  __shared__ __align__(16) unsigned short ptl[24 * 256];
  int wg = xcd_swz(blockIdx.x, gridDim.x);
  int c24 = wg & 7, rp = (wg >> 3) & 63, b = wg >> 9;
  int y0 = rp * 2, g0 = c24 * 24;
  int tid = threadIdx.x;
  for (int i = tid; i < 9504; i += 256) ((unsigned int*)vb)[i] = 0;
  __syncthreads();
#pragma unroll
  for (int i = 0; i < 9; ++i) {
    int f = tid + i * 256;   // 2304 = 768 px * 3 slots
    int slot = f % 3, pxl = f / 3;
    int r = pxl >> 7, xx = pxl & 127;
    int yy = y0 - 2 + r;
    if (yy >= 0 && yy < HGT) {
      int p = yy * WID + xx;
      uint4 v = *(const uint4*)(vT + ((size_t)b * HW + p) * 384 + (((3 * c24 + slot) ^ (p & 7)) * 16));
      unsigned int uu[4] = {v.x, v.y, v.z, v.w};
#pragma unroll
      for (int e = 0; e < 4; ++e) {
        vb[(slot * 8 + 2 * e) * 792 + r * 132 + xx + 2] = (unsigned short)(uu[e] & 0xffff);
        vb[(slot * 8 + 2 * e + 1) * 792 + r * 132 + xx + 2] = (unsigned short)(uu[e] >> 16);
      }
    }
  }
  __syncthreads();
#pragma unroll
  for (int ch = 0; ch < 24; ++ch) {
    const float* wv = w1 + (g0 + ch) * 9;
    for (int it = 0; it < 3; ++it) {
      int f = tid + it * 256;
      if (f < 520) {
        int r = f / 130, xh = f % 130;
        float gel = 0.f;
        int ximg = xh - 1, yimg = y0 - 1 + r;
        if (ximg >= 0 && ximg < WID && yimg >= 0 && yimg < HGT) {
          float acc = 0.f;
#pragma unroll
          for (int dy = 0; dy < 3; ++dy)
#pragma unroll
            for (int dx = 0; dx < 3; ++dx)
              acc += bf2f(vb[ch * 792 + (r + dy) * 132 + xh + dx]) * wv[dy * 3 + dx];
          gel = 0.5f * acc * (1.0f + erff(acc * 0.70710678118f));
        }
        d1[ch * 520 + f] = f2bf(gel);
      }
    }
  }
  __syncthreads();
  {
    int yy = tid >> 7, xx2 = tid & 127;
#pragma unroll
    for (int ch = 0; ch < 24; ++ch) {
      const float* wv = w2 + (g0 + ch) * 9;
      float acc = 0.f;
#pragma unroll
      for (int dy = 0; dy < 3; ++dy)
#pragma unroll
        for (int dx = 0; dx < 3; ++dx)
          acc += bf2f(d1[ch * 520 + (yy + dy) * 130 + xx2 + dx]) * wv[dy * 3 + dx];
      ptl[ch * 256 + tid] = f2bf(acc);
    }
  }
  __syncthreads();
#pragma unroll
  for (int i = 0; i < 3; ++i) {
    int f = tid + i * 256;   // 768 = 24ch x 32 segs
    int ch = f >> 5, seg = f & 31;
    uint4 v = *(const uint4*)(ptl + ch * 256 + seg * 8);
    *(uint4*)((unsigned char*)pos + (((size_t)(b * CC + g0 + ch)) * HW + y0 * WID + seg * 8) * 2) = v;
  }
}

// ---------------- kproj: out[b][oc][p] = sum_g W2[oc][g]*v[g][p] + bproj + pos  (f32 out)
__global__ __launch_bounds__(256) void kproj(const unsigned char* __restrict__ vT,
                                             const unsigned char* __restrict__ W2,
                                             const float* __restrict__ bproj,
                                             const unsigned short* __restrict__ pos,
                                             float* __restrict__ out) {
  __shared__ __align__(16) unsigned char lds[73728];
  int wg = xcd_swz(blockIdx.x, gridDim.x);
  int ot = wg % 3;
  int pt = (wg / 3) & 127;
  int b = wg / 384;
  int tid = threadIdx.x;
  const unsigned char* gA = vT + ((size_t)b * HW + pt * 128) * 384;
  const unsigned char* gB = W2 + ((size_t)(b * CC + ot * 64)) * 384;
#pragma unroll
  for (int i = 0; i < 12; ++i)
    gl_lds16(gA + i * 4096 + tid * 16, lds + i * 4096 + tid * 16);
#pragma unroll
  for (int i = 0; i < 6; ++i)
    gl_lds16(gB + i * 4096 + tid * 16, lds + 49152 + i * 4096 + tid * 16);
  asm volatile("s_waitcnt vmcnt(0)" ::: "memory");
  __syncthreads();

  int lane = tid & 63, wv = tid >> 6;
  int l15 = lane & 15, gq = lane >> 4;
  int pw = (wv >> 1) * 64, ow = (wv & 1) * 32;
  f32x4 acc[4][2];
#pragma unroll
  for (int a = 0; a < 4; ++a)
#pragma unroll
    for (int c = 0; c < 2; ++c) acc[a][c] = (f32x4){0.f, 0.f, 0.f, 0.f};

#pragma unroll
  for (int kk = 0; kk < 6; ++kk) {
    int cb = kk * 64 + gq * 16;
    bf16x8 af[4], bfr[2];
#pragma unroll
    for (int mf = 0; mf < 4; ++mf) {
      int r = pw + mf * 16 + l15;
      af[mf] = *(const bf16x8*)(lds + r * 384 + (cb ^ ((r & 7) << 4)));
    }
#pragma unroll
    for (int nf = 0; nf < 2; ++nf) {
      int r = ow + nf * 16 + l15;
      bfr[nf] = *(const bf16x8*)(lds + 49152 + r * 384 + (cb ^ ((r & 7) << 4)));
    }
#pragma unroll
    for (int mf = 0; mf < 4; ++mf)
#pragma unroll
      for (int nf = 0; nf < 2; ++nf)
        acc[mf][nf] = __builtin_amdgcn_mfma_f32_16x16x32_bf16(af[mf], bfr[nf], acc[mf][nf], 0, 0, 0);
  }
#pragma unroll
  for (int nf = 0; nf < 2; ++nf) {
    int oc = ot * 64 + ow + nf * 16 + l15;
    float bias = bproj[oc];
    size_t rowb = ((size_t)b * CC + oc) * HW;
#pragma unroll
    for (int mf = 0; mf < 4; ++mf) {
      int p = pt * 128 + pw + mf * 16 + gq * 4;
      uint2 pv = *(const uint2*)(pos + rowb + p);
      float4 o;
      o.x = acc[mf][nf][0] + bias + bf2f((unsigned short)(pv.x & 0xffff));
      o.y = acc[mf][nf][1] + bias + bf2f((unsigned short)(pv.x >> 16));
      o.z = acc[mf][nf][2] + bias + bf2f((unsigned short)(pv.y & 0xffff));
      o.w = acc[mf][nf][3] + bias + bf2f((unsigned short)(pv.y >> 16));
      *(float4*)(out + rowb + p) = o;
    }
  }
}

// ---------------- workspace layout ----------------
#define OFF_W   ((size_t)0)                    // 221184
#define OFF_G   ((size_t)221184)               // 147456
#define OFF_NQ  ((size_t)368640)               // 6144
#define OFF_NK  ((size_t)374784)               // 6144
#define OFF_W2  ((size_t)380928)               // 589824
#define OFF_T   ((size_t)970752)               // 150994944 (t; reused for pos)
#define OFF_XT  ((size_t)151965696)            // 50331648  (xT; reused for vT)

extern "C" void kernel_launch(void* const* d_in, const int* in_sizes, int n_in,
                              void* d_out, int out_size, void* d_ws, size_t ws_size,
                              hipStream_t stream) {
  const float* x     = (const float*)d_in[0];
  const float* wqkv  = (const float*)d_in[1];
  const float* bqkv  = (const float*)d_in[2];
  const float* wdw   = (const float*)d_in[3];
  const float* bdw   = (const float*)d_in[4];
  const float* wproj = (const float*)d_in[5];
  const float* bproj = (const float*)d_in[6];
  const float* wpos1 = (const float*)d_in[7];
  const float* wpos2 = (const float*)d_in[8];
  const float* temp  = (const float*)d_in[9];
  unsigned char* ws = (unsigned char*)d_ws;

  hipMemsetAsync(ws + OFF_G, 0, 147456 + 6144 + 6144, stream);
  kwprep<<<54, 256, 0, stream>>>(wqkv, ws + OFF_W);
  ktrans<<<2048, 256, 0, stream>>>(x, (unsigned short*)(ws + OFF_XT));
  kconv1<<<9216, 256, 0, stream>>>(ws + OFF_XT, ws + OFF_W, bqkv,
                                   (unsigned short*)(ws + OFF_T));
  kdw<<<4096, 256, 0, stream>>>((const unsigned short*)(ws + OFF_T), wdw, bdw,
                                ws + OFF_XT /* vT overwrites xT */,
                                (float*)(ws + OFF_G), (float*)(ws + OFF_NQ),
                                (float*)(ws + OFF_NK));
  kattn<<<64, 256, 0, stream>>>((const float*)(ws + OFF_G), (const float*)(ws + OFF_NQ),
                                (const float*)(ws + OFF_NK), temp, wproj, ws + OFF_W2);
  kpos<<<4096, 256, 0, stream>>>(ws + OFF_XT, wpos1, wpos2,
                                 (unsigned short*)(ws + OFF_T) /* pos overwrites t */);
  kproj<<<3072, 256, 0, stream>>>(ws + OFF_XT, ws + OFF_W2, bproj,
                                  (const unsigned short*)(ws + OFF_T), (float*)d_out);
}

// Round 2
// 351.969 us; speedup vs baseline: 2.1864x; 2.1864x over previous
//
#include <hip/hip_runtime.h>
#include <stdint.h>
#include <stddef.h>

#define NB 8
#define CC 192
#define C3 576
#define HGT 128
#define WID 128
#define HW 16384
#define NH 8

typedef short bf16x8 __attribute__((ext_vector_type(8)));
typedef float f32x4 __attribute__((ext_vector_type(4)));

__device__ __forceinline__ unsigned short f2bf(float f) {
  unsigned int u = __float_as_uint(f);
  u += 0x7fffu + ((u >> 16) & 1u);
  return (unsigned short)(u >> 16);
}
__device__ __forceinline__ float bf2f(unsigned short h) {
  return __uint_as_float(((unsigned int)h) << 16);
}
__device__ __forceinline__ unsigned int pk2(float a, float b) {
  return (unsigned int)f2bf(a) | ((unsigned int)f2bf(b) << 16);
}
__device__ __forceinline__ void gl_lds16(const void* g, void* l) {
  __builtin_amdgcn_global_load_lds(
      (const __attribute__((address_space(1))) unsigned int*)(uintptr_t)g,
      (__attribute__((address_space(3))) unsigned int*)(uint32_t)(uintptr_t)l,
      16, 0, 0);
}
__device__ __forceinline__ int xcd_swz(int g, int n) {
  return (g & 7) * (n >> 3) + (g >> 3);
}

// ---------------- ktrans: x [b][192][HW] f32 -> xT slot-planar [b][24][HW][16B] bf16
__global__ __launch_bounds__(256) void ktrans(const float* __restrict__ x,
                                              unsigned char* __restrict__ xT) {
  __shared__ __align__(16) float lx[192 * 68];
  int wg = xcd_swz(blockIdx.x, gridDim.x);
  int pt = wg & 255, b = wg >> 8;
  int p0 = pt * 64;
  int tid = threadIdx.x;
#pragma unroll
  for (int i = 0; i < 12; ++i) {
    int f = tid + i * 256;
    int ic = f >> 4, q = f & 15;
    float4 v = *(const float4*)(x + ((size_t)(b * CC + ic)) * HW + p0 + q * 4);
    *(float4*)(lx + ic * 68 + q * 4) = v;
  }
  __syncthreads();
#pragma unroll
  for (int i = 0; i < 6; ++i) {
    int f = i * 256 + tid;          // 1536 = 24 slots * 64 px
    int s = f >> 6, p = f & 63;
    unsigned int wv[4];
#pragma unroll
    for (int j = 0; j < 4; ++j)
      wv[j] = pk2(lx[(s * 8 + 2 * j) * 68 + p], lx[(s * 8 + 2 * j + 1) * 68 + p]);
    uint4 st; st.x = wv[0]; st.y = wv[1]; st.z = wv[2]; st.w = wv[3];
    *(uint4*)(xT + (((size_t)(b * 24 + s)) * HW + p0 + p) * 16) = st;
  }
}

// ---------------- kwprep: w_qkv [576][192] f32 -> bf16 swizzled rows
__global__ void kwprep(const float* __restrict__ wq, unsigned char* __restrict__ wb) {
  int f = blockIdx.x * 256 + threadIdx.x;
  if (f >= C3 * 24) return;
  int oc = f / 24, s = f % 24;
  unsigned int wv[4];
#pragma unroll
  for (int j = 0; j < 4; ++j)
    wv[j] = pk2(wq[oc * 192 + s * 8 + 2 * j], wq[oc * 192 + s * 8 + 2 * j + 1]);
  uint4 st; st.x = wv[0]; st.y = wv[1]; st.z = wv[2]; st.w = wv[3];
  *(uint4*)(wb + (size_t)oc * 384 + ((s ^ (oc & 7)) * 16)) = st;
}

// ---------------- kconv1: t[part][b][c][p] = qkv conv1x1 (bf16 MFMA)
__global__ __launch_bounds__(256) void kconv1(const unsigned char* __restrict__ xT,
                                              const unsigned char* __restrict__ wb,
                                              const float* __restrict__ bqkv,
                                              unsigned short* __restrict__ t) {
  __shared__ __align__(16) unsigned char lds[73728]; // A:49152 linear  B:24576 swz
  int wg = xcd_swz(blockIdx.x, gridDim.x);
  int ot = wg % 9;
  int pt = (wg / 9) & 127;
  int b = wg / 1152;
  int tid = threadIdx.x;
  const unsigned char* gB = wb + (size_t)ot * 64 * 384;
#pragma unroll
  for (int i = 0; i < 12; ++i) {
    int u2 = i * 256 + tid;
    int slot = u2 >> 7, px = u2 & 127;
    gl_lds16(xT + (((size_t)(b * 24 + slot)) * HW + pt * 128 + px) * 16, lds + u2 * 16);
  }
#pragma unroll
  for (int i = 0; i < 6; ++i)
    gl_lds16(gB + i * 4096 + tid * 16, lds + 49152 + i * 4096 + tid * 16);
  asm volatile("s_waitcnt vmcnt(0)" ::: "memory");
  __syncthreads();

  int lane = tid & 63, wv = tid >> 6;
  int l15 = lane & 15, gq = lane >> 4;
  int pw = (wv >> 1) * 64, ow = (wv & 1) * 32;
  f32x4 acc[4][2];
#pragma unroll
  for (int a = 0; a < 4; ++a)
#pragma unroll
    for (int c = 0; c < 2; ++c) acc[a][c] = (f32x4){0.f, 0.f, 0.f, 0.f};

#pragma unroll
  for (int kk = 0; kk < 6; ++kk) {
    int cb = kk * 64 + gq * 16;
    bf16x8 af[4], bfr[2];
#pragma unroll
    for (int mf = 0; mf < 4; ++mf)
      af[mf] = *(const bf16x8*)(lds + (((kk * 4 + gq) << 7) + pw + mf * 16 + l15) * 16);
#pragma unroll
    for (int nf = 0; nf < 2; ++nf) {
      int r = ow + nf * 16 + l15;
      bfr[nf] = *(const bf16x8*)(lds + 49152 + r * 384 + (cb ^ ((r & 7) << 4)));
    }
#pragma unroll
    for (int mf = 0; mf < 4; ++mf)
#pragma unroll
      for (int nf = 0; nf < 2; ++nf)
        acc[mf][nf] = __builtin_amdgcn_mfma_f32_16x16x32_bf16(af[mf], bfr[nf], acc[mf][nf], 0, 0, 0);
  }
#pragma unroll
  for (int nf = 0; nf < 2; ++nf) {
    int oc = ot * 64 + ow + nf * 16 + l15;
    float bias = bqkv[oc];
    int part = oc / 192, c = oc % 192;
    size_t rowb = ((size_t)((part * 8 + b) * CC + c)) * HW;
#pragma unroll
    for (int mf = 0; mf < 4; ++mf) {
      int p = pt * 128 + pw + mf * 16 + gq * 4;
      uint2 st;
      st.x = pk2(acc[mf][nf][0] + bias, acc[mf][nf][1] + bias);
      st.y = pk2(acc[mf][nf][2] + bias, acc[mf][nf][3] + bias);
      *(uint2*)(t + rowb + p) = st;
    }
  }
}

// ---------------- kdw: depthwise 3x3 over one part (8ch x 8rows x 128cols per block)
// mode 0: planar out + sq-norm atomics ; mode 1: vT slot-planar out
__global__ __launch_bounds__(256) void kdw(const unsigned short* __restrict__ src,
                                           const float* __restrict__ wdw,
                                           const float* __restrict__ bdw,
                                           int part, int mode,
                                           unsigned short* __restrict__ dst,
                                           float* __restrict__ nrm,
                                           unsigned char* __restrict__ vT) {
  __shared__ __align__(16) unsigned int smem[8 * 721];   // 23072 B
  int wg = xcd_swz(blockIdx.x, gridDim.x);
  int cg = wg % 24, rt = (wg / 24) & 15, b = wg / 384;
  int y0 = rt * 8, chg0 = cg * 8;
  int tid = threadIdx.x;
  for (int i = tid; i < 5768; i += 256) smem[i] = 0;
  __syncthreads();
  // stage rows y0-1..y0+8 at cx = x+8 (u16), row stride 72 u32, ch stride 721 u32
#pragma unroll
  for (int i = 0; i < 5; ++i) {
    int f = i * 256 + tid;          // 1280 = 8ch*10r*16seg
    int ch = f / 160, rem = f % 160;
    int r = rem >> 4, seg = rem & 15;
    int y = y0 - 1 + r;
    if (y >= 0 && y < HGT) {
      uint4 v = *(const uint4*)(src + ((size_t)(b * CC + chg0 + ch)) * HW + y * WID + seg * 8);
      unsigned int* dp = smem + ch * 721 + r * 72 + 4 + seg * 4;
      dp[0] = v.x; dp[1] = v.y; dp[2] = v.z; dp[3] = v.w;
    }
  }
  __syncthreads();

  int ch = tid >> 5, u = tid & 31;
  int row = u >> 2, xs = (u & 3) * 32;
  int gch = part * CC + chg0 + ch;
  float wv[9];
#pragma unroll
  for (int j = 0; j < 9; ++j) wv[j] = wdw[gch * 9 + j];
  float bias = bdw[gch];
  float outv[32];
  const unsigned int* tb = smem + ch * 721;
#pragma unroll
  for (int g = 0; g < 4; ++g) {
    int x0 = xs + g * 8;
    float v[3][12];
#pragma unroll
    for (int dy = 0; dy < 3; ++dy) {
      const unsigned int* rp = tb + (row + dy) * 72 + ((x0 + 6) >> 1);
#pragma unroll
      for (int m = 0; m < 6; ++m) {
        unsigned int w2 = rp[m];
        v[dy][2 * m] = bf2f((unsigned short)(w2 & 0xffff));
        v[dy][2 * m + 1] = bf2f((unsigned short)(w2 >> 16));
      }
    }
#pragma unroll
    for (int j = 0; j < 8; ++j) {
      float a = bias;
#pragma unroll
      for (int dy = 0; dy < 3; ++dy)
#pragma unroll
        for (int dx = 0; dx < 3; ++dx)
          a += v[dy][j + dx + 1] * wv[dy * 3 + dx];
      outv[g * 8 + j] = a;
    }
  }

  if (mode == 0) {
    size_t rb = ((size_t)(b * CC + chg0 + ch)) * HW + (size_t)(y0 + row) * WID + xs;
#pragma unroll
    for (int g = 0; g < 4; ++g) {
      uint4 st;
      st.x = pk2(outv[g * 8 + 0], outv[g * 8 + 1]);
      st.y = pk2(outv[g * 8 + 2], outv[g * 8 + 3]);
      st.z = pk2(outv[g * 8 + 4], outv[g * 8 + 5]);
      st.w = pk2(outv[g * 8 + 6], outv[g * 8 + 7]);
      *(uint4*)(dst + rb + g * 8) = st;
    }
    float s = 0.f;
#pragma unroll
    for (int i = 0; i < 32; ++i) s += outv[i] * outv[i];
#pragma unroll
    for (int m = 16; m >= 1; m >>= 1) s += __shfl_xor(s, m, 32);
    if (u == 0) {
      int qc = chg0 + ch;
      atomicAdd(nrm + (b * NH + qc / 24) * 24 + (qc % 24), s);
    }
  } else {
    __syncthreads();
    unsigned short* vt = (unsigned short*)smem;   // [8][8][128] u16
#pragma unroll
    for (int g = 0; g < 4; ++g)
#pragma unroll
      for (int j = 0; j < 8; j += 2) {
        int x = xs + g * 8 + j;
        ((unsigned int*)smem)[ch * 512 + row * 64 + (x >> 1)] =
            pk2(outv[g * 8 + j], outv[g * 8 + j + 1]);
      }
    __syncthreads();
#pragma unroll
    for (int i = 0; i < 4; ++i) {
      int f = i * 256 + tid;        // 1024 px
      int r = f >> 7, col = f & 127;
      unsigned int wvp[4];
#pragma unroll
      for (int e = 0; e < 4; ++e) {
        unsigned short a = vt[(2 * e) * 1024 + r * 128 + col];
        unsigned short bb = vt[(2 * e + 1) * 1024 + r * 128 + col];
        wvp[e] = (unsigned int)a | ((unsigned int)bb << 16);
      }
      uint4 st; st.x = wvp[0]; st.y = wvp[1]; st.z = wvp[2]; st.w = wvp[3];
      *(uint4*)(vT + (((size_t)(b * 24 + cg)) * HW + (size_t)(y0 + r) * WID + col) * 16) = st;
    }
  }
}

// ---------------- kgram: G[b][h][24][24] += q . k^T  (MFMA, K chunks of 512)
__global__ __launch_bounds__(256) void kgram(const unsigned short* __restrict__ q,
                                             const unsigned short* __restrict__ k,
                                             float* __restrict__ G) {
  __shared__ __align__(16) unsigned char qt[32768];   // [32][512] bf16 swz
  __shared__ __align__(16) unsigned char kt[32768];
  __shared__ float gpart[4][32][32];
  int blk = blockIdx.x;
  int b = blk >> 5, h = (blk >> 2) & 7, qr = blk & 3;
  int tid = threadIdx.x, lane = tid & 63, w = tid >> 6;
  int l15 = lane & 15, gq = lane >> 4;
  for (int i = tid; i < 2048; i += 256) {   // zero rows 24..31
    ((unsigned int*)(qt + 24576))[i] = 0;
    ((unsigned int*)(kt + 24576))[i] = 0;
  }
  f32x4 acc[2][2];
#pragma unroll
  for (int a = 0; a < 2; ++a)
#pragma unroll
    for (int d = 0; d < 2; ++d) acc[a][d] = (f32x4){0.f, 0.f, 0.f, 0.f};
  for (int c = 0; c < 8; ++c) {
    __syncthreads();
    int px0 = qr * 4096 + c * 512;
#pragma unroll
    for (int i = 0; i < 6; ++i) {
      int f = i * 256 + tid;        // 1536 = 24 rows * 64 seg
      int rowc = f >> 6, seg = f & 63;
      size_t gofs = ((size_t)(b * CC + h * 24 + rowc)) * HW + px0 + seg * 8;
      unsigned int lofs = rowc * 1024 + ((seg * 16) ^ ((rowc & 7) << 4));
      *(uint4*)(qt + lofs) = *(const uint4*)(q + gofs);
      *(uint4*)(kt + lofs) = *(const uint4*)(k + gofs);
    }
    __syncthreads();
#pragma unroll
    for (int j = 0; j < 4; ++j) {
      int kk = w * 4 + j;
      int cb = kk * 64 + gq * 16;
      bf16x8 aq[2], bk[2];
#pragma unroll
      for (int ct = 0; ct < 2; ++ct) {
        int r = ct * 16 + l15;
        aq[ct] = *(const bf16x8*)(qt + r * 1024 + (cb ^ ((r & 7) << 4)));
        bk[ct] = *(const bf16x8*)(kt + r * 1024 + (cb ^ ((r & 7) << 4)));
      }
#pragma unroll
      for (int ct = 0; ct < 2; ++ct)
#pragma unroll
        for (int dt = 0; dt < 2; ++dt)
          acc[ct][dt] = __builtin_amdgcn_mfma_f32_16x16x32_bf16(aq[ct], bk[dt], acc[ct][dt], 0, 0, 0);
    }
  }
  __syncthreads();
#pragma unroll
  for (int ct = 0; ct < 2; ++ct)
#pragma unroll
    for (int dt = 0; dt < 2; ++dt)
#pragma unroll
      for (int r = 0; r < 4; ++r)
        gpart[w][ct * 16 + gq * 4 + r][dt * 16 + l15] = acc[ct][dt][r];
  __syncthreads();
  for (int f = tid; f < 576; f += 256) {
    int cc2 = f / 24, d = f % 24;
    float s = gpart[0][cc2][d] + gpart[1][cc2][d] + gpart[2][cc2][d] + gpart[3][cc2][d];
    atomicAdd(G + ((size_t)(b * NH + h)) * 576 + cc2 * 24 + d, s);
  }
}

// ---------------- kattn: softmax + fold w_proj -> W2[b] (bf16 swz rows)
__global__ __launch_bounds__(256) void kattn(const float* __restrict__ G,
                                             const float* __restrict__ nq,
                                             const float* __restrict__ nk,
                                             const float* __restrict__ temp,
                                             const float* __restrict__ wproj,
                                             unsigned char* __restrict__ W2) {
  __shared__ float attn[24][24];
  __shared__ float iq[24], ik[24];
  int bh = blockIdx.x;
  int h = bh & 7, b = bh >> 3;
  int tid = threadIdx.x;
  const float* Gb = G + (size_t)bh * 576;
  if (tid < 24) { float n = sqrtf(nq[bh * 24 + tid]); iq[tid] = 1.f / fmaxf(n, 1e-12f); }
  else if (tid < 48) { float n = sqrtf(nk[bh * 24 + tid - 24]); ik[tid - 24] = 1.f / fmaxf(n, 1e-12f); }
  __syncthreads();
  if (tid < 24) {
    float tmp = temp[h];
    float row[24];
    float mx = -1e30f;
#pragma unroll
    for (int d = 0; d < 24; ++d) {
      row[d] = Gb[tid * 24 + d] * iq[tid] * ik[d] * tmp;
      mx = fmaxf(mx, row[d]);
    }
    float sum = 0.f;
#pragma unroll
    for (int d = 0; d < 24; ++d) { float e = expf(row[d] - mx); row[d] = e; sum += e; }
    float inv = 1.f / sum;
#pragma unroll
    for (int d = 0; d < 24; ++d) attn[tid][d] = row[d] * inv;
  }
  __syncthreads();
  for (int i = 0; i < 18; ++i) {
    int f = tid + i * 256;
    if (f >= 4608) break;
    int oc = f / 24, d = f % 24;
    float s = 0.f;
#pragma unroll
    for (int c = 0; c < 24; ++c) s += wproj[oc * 192 + h * 24 + c] * attn[c][d];
    int gg = h * 24 + d;
    *(unsigned short*)(W2 + ((size_t)b * CC + oc) * 384 + ((gg * 2) ^ ((oc & 7) << 4))) = f2bf(s);
  }
}

// ---------------- kpos: pos = dwconv(gelu(dwconv(v,w1)),w2) ; v from vT slot-planar
__global__ __launch_bounds__(256) void kpos(const unsigned char* __restrict__ vT,
                                            const float* __restrict__ w1,
                                            const float* __restrict__ w2,
                                            unsigned short* __restrict__ pos) {
  __shared__ unsigned int vbuf[8 * 865];   // [8ch][12r][144 u16] (ch stride 865 u32)
  __shared__ unsigned int d1[8 * 721];     // [8ch][10r][144 u16] (ch stride 721 u32)
  int wg = xcd_swz(blockIdx.x, gridDim.x);
  int cg = wg % 24, rt = (wg / 24) & 15, b = wg / 384;
  int y0 = rt * 8, g0 = cg * 8;
  int tid = threadIdx.x;
  for (int i = tid; i < 6920; i += 256) vbuf[i] = 0;
  __syncthreads();
  // stage v rows y0-2..y0+9 (12), cols 0..127 at cx = x+8
#pragma unroll
  for (int i = 0; i < 3; ++i) {
    int f = i * 256 + tid;          // 768 px-pairs
    int r = f >> 6, colp = f & 63;
    int y = y0 - 2 + r;
    if (y >= 0 && y < HGT) {
      const unsigned char* base = vT + (((size_t)(b * 24 + cg)) * HW + (size_t)y * WID + colp * 2) * 16;
      uint4 va = *(const uint4*)(base);
      uint4 vb2 = *(const uint4*)(base + 16);
      unsigned int la[4] = {va.x, va.y, va.z, va.w};
      unsigned int lb[4] = {vb2.x, vb2.y, vb2.z, vb2.w};
#pragma unroll
      for (int e = 0; e < 8; ++e) {
        unsigned int a16 = (la[e >> 1] >> ((e & 1) * 16)) & 0xffff;
        unsigned int b16 = (lb[e >> 1] >> ((e & 1) * 16)) & 0xffff;
        vbuf[e * 865 + r * 72 + colp + 4] = a16 | (b16 << 16);
      }
    }
  }
  __syncthreads();
  // conv1 + gelu -> d1 rows y0-1..y0+8 (10), x in 0..127 (+ edges x=-1,128)
  int ch = tid >> 5, u = tid & 31;
  {
    const float* wp = w1 + (g0 + ch) * 9;
    float wl[9];
#pragma unroll
    for (int j = 0; j < 9; ++j) wl[j] = wp[j];
    int x0 = u * 4;
    for (int rr = 0; rr < 10; ++rr) {
      int y = y0 - 1 + rr;
      unsigned int o0 = 0, o1 = 0;
      if (y >= 0 && y < HGT) {
        float v[3][8];
#pragma unroll
        for (int dy = 0; dy < 3; ++dy) {
          const unsigned int* rp = vbuf + ch * 865 + (rr + dy) * 72 + ((x0 + 6) >> 1);
#pragma unroll
          for (int m = 0; m < 4; ++m) {
            unsigned int w2r = rp[m];
            v[dy][2 * m] = bf2f((unsigned short)(w2r & 0xffff));
            v[dy][2 * m + 1] = bf2f((unsigned short)(w2r >> 16));
          }
        }
        float g4[4];
#pragma unroll
        for (int j = 0; j < 4; ++j) {
          float a = 0.f;
#pragma unroll
          for (int dy = 0; dy < 3; ++dy)
#pragma unroll
            for (int dx = 0; dx < 3; ++dx)
              a += v[dy][j + dx + 1] * wl[dy * 3 + dx];
          g4[j] = 0.5f * a * (1.f + erff(a * 0.70710678118f));
        }
        o0 = pk2(g4[0], g4[1]);
        o1 = pk2(g4[2], g4[3]);
      }
      unsigned int* dp = d1 + ch * 721 + rr * 72 + ((x0 + 8) >> 1);
      dp[0] = o0; dp[1] = o1;
    }
  }
  // edge cols x = -1 and x = 128 (feed conv2 outputs x=0 / x=127)
  if (tid < 160) {
    int ech = tid / 20, rem = tid % 20;
    int rr = rem >> 1, side = rem & 1;
    int x = side ? 128 : -1;
    int y = y0 - 1 + rr;
    unsigned short val = 0;
    if (y >= 0 && y < HGT) {
      const float* wp = w1 + (g0 + ech) * 9;
      float a = 0.f;
      const unsigned short* vb16 = (const unsigned short*)(vbuf + ech * 865);
#pragma unroll
      for (int dy = 0; dy < 3; ++dy)
#pragma unroll
        for (int dx = 0; dx < 3; ++dx)
          a += bf2f(vb16[(rr + dy) * 144 + (x + dx + 7)]) * wp[dy * 3 + dx];
      val = f2bf(0.5f * a * (1.f + erff(a * 0.70710678118f)));
    }
    ((unsigned short*)(d1 + ech * 721))[rr * 144 + (x + 8)] = val;
  }
  __syncthreads();
  // conv2 -> pos (8ch x 8rows x 128)
  {
    const float* wp = w2 + (g0 + ch) * 9;
    float wl[9];
#pragma unroll
    for (int j = 0; j < 9; ++j) wl[j] = wp[j];
    int row = u >> 2, xs = (u & 3) * 32;
    size_t rb = ((size_t)(b * CC + g0 + ch)) * HW + (size_t)(y0 + row) * WID;
#pragma unroll
    for (int g = 0; g < 4; ++g) {
      int x0 = xs + g * 8;
      float v[3][12];
#pragma unroll
      for (int dy = 0; dy < 3; ++dy) {
        const unsigned int* rp = d1 + ch * 721 + (row + dy) * 72 + ((x0 + 6) >> 1);
#pragma unroll
        for (int m = 0; m < 6; ++m) {
          unsigned int w2r = rp[m];
          v[dy][2 * m] = bf2f((unsigned short)(w2r & 0xffff));
          v[dy][2 * m + 1] = bf2f((unsigned short)(w2r >> 16));
        }
      }
      uint4 st;
      float o[8];
#pragma unroll
      for (int j = 0; j < 8; ++j) {
        float a = 0.f;
#pragma unroll
        for (int dy = 0; dy < 3; ++dy)
#pragma unroll
          for (int dx = 0; dx < 3; ++dx)
            a += v[dy][j + dx + 1] * wl[dy * 3 + dx];
        o[j] = a;
      }
      st.x = pk2(o[0], o[1]); st.y = pk2(o[2], o[3]);
      st.z = pk2(o[4], o[5]); st.w = pk2(o[6], o[7]);
      *(uint4*)(pos + rb + x0) = st;
    }
  }
}

// ---------------- kproj: out = W2 . v + bproj + pos  (f32 out)
__global__ __launch_bounds__(256) void kproj(const unsigned char* __restrict__ vT,
                                             const unsigned char* __restrict__ W2,
                                             const float* __restrict__ bproj,
                                             const unsigned short* __restrict__ pos,
                                             float* __restrict__ out) {
  __shared__ __align__(16) unsigned char lds[73728];
  int wg = xcd_swz(blockIdx.x, gridDim.x);
  int ot = wg % 3;
  int pt = (wg / 3) & 127;
  int b = wg / 384;
  int tid = threadIdx.x;
  const unsigned char* gB = W2 + ((size_t)(b * CC + ot * 64)) * 384;
#pragma unroll
  for (int i = 0; i < 12; ++i) {
    int u2 = i * 256 + tid;
    int slot = u2 >> 7, px = u2 & 127;
    gl_lds16(vT + (((size_t)(b * 24 + slot)) * HW + pt * 128 + px) * 16, lds + u2 * 16);
  }
#pragma unroll
  for (int i = 0; i < 6; ++i)
    gl_lds16(gB + i * 4096 + tid * 16, lds + 49152 + i * 4096 + tid * 16);
  asm volatile("s_waitcnt vmcnt(0)" ::: "memory");
  __syncthreads();

  int lane = tid & 63, wv = tid >> 6;
  int l15 = lane & 15, gq = lane >> 4;
  int pw = (wv >> 1) * 64, ow = (wv & 1) * 32;
  f32x4 acc[4][2];
#pragma unroll
  for (int a = 0; a < 4; ++a)
#pragma unroll
    for (int c = 0; c < 2; ++c) acc[a][c] = (f32x4){0.f, 0.f, 0.f, 0.f};

#pragma unroll
  for (int kk = 0; kk < 6; ++kk) {
    int cb = kk * 64 + gq * 16;
    bf16x8 af[4], bfr[2];
#pragma unroll
    for (int mf = 0; mf < 4; ++mf)
      af[mf] = *(const bf16x8*)(lds + (((kk * 4 + gq) << 7) + pw + mf * 16 + l15) * 16);
#pragma unroll
    for (int nf = 0; nf < 2; ++nf) {
      int r = ow + nf * 16 + l15;
      bfr[nf] = *(const bf16x8*)(lds + 49152 + r * 384 + (cb ^ ((r & 7) << 4)));
    }
#pragma unroll
    for (int mf = 0; mf < 4; ++mf)
#pragma unroll
      for (int nf = 0; nf < 2; ++nf)
        acc[mf][nf] = __builtin_amdgcn_mfma_f32_16x16x32_bf16(af[mf], bfr[nf], acc[mf][nf], 0, 0, 0);
  }
#pragma unroll
  for (int nf = 0; nf < 2; ++nf) {
    int oc = ot * 64 + ow + nf * 16 + l15;
    float bias = bproj[oc];
    size_t rowb = ((size_t)(b * CC + oc)) * HW;
#pragma unroll
    for (int mf = 0; mf < 4; ++mf) {
      int p = pt * 128 + pw + mf * 16 + gq * 4;
      uint2 pv = *(const uint2*)(pos + rowb + p);
      float4 o;
      o.x = acc[mf][nf][0] + bias + bf2f((unsigned short)(pv.x & 0xffff));
      o.y = acc[mf][nf][1] + bias + bf2f((unsigned short)(pv.x >> 16));
      o.z = acc[mf][nf][2] + bias + bf2f((unsigned short)(pv.y & 0xffff));
      o.w = acc[mf][nf][3] + bias + bf2f((unsigned short)(pv.y >> 16));
      *(float4*)(out + rowb + p) = o;
    }
  }
}

// ---------------- workspace layout ----------------
#define OFF_W   ((size_t)0)                    // 221184
#define OFF_G   ((size_t)221184)               // 147456
#define OFF_NQ  ((size_t)368640)               // 6144
#define OFF_NK  ((size_t)374784)               // 6144
#define OFF_W2  ((size_t)380928)               // 589824
#define OFF_T   ((size_t)970752)               // 150994944 : t[3 parts][b][192][HW] bf16
#define OFF_XT  ((size_t)151965696)            // 50331648  : xT/vT slot-planar

#define PART_ELEMS ((size_t)8 * CC * HW)       // 25165824 bf16 elems per part

extern "C" void kernel_launch(void* const* d_in, const int* in_sizes, int n_in,
                              void* d_out, int out_size, void* d_ws, size_t ws_size,
                              hipStream_t stream) {
  const float* x     = (const float*)d_in[0];
  const float* wqkv  = (const float*)d_in[1];
  const float* bqkv  = (const float*)d_in[2];
  const float* wdw   = (const float*)d_in[3];
  const float* bdw   = (const float*)d_in[4];
  const float* wproj = (const float*)d_in[5];
  const float* bproj = (const float*)d_in[6];
  const float* wpos1 = (const float*)d_in[7];
  const float* wpos2 = (const float*)d_in[8];
  const float* temp  = (const float*)d_in[9];
  unsigned char* ws = (unsigned char*)d_ws;
  unsigned short* t = (unsigned short*)(ws + OFF_T);

  hipMemsetAsync(ws + OFF_G, 0, 147456 + 6144 + 6144, stream);
  kwprep<<<54, 256, 0, stream>>>(wqkv, ws + OFF_W);
  ktrans<<<2048, 256, 0, stream>>>(x, ws + OFF_XT);
  kconv1<<<9216, 256, 0, stream>>>(ws + OFF_XT, ws + OFF_W, bqkv, t);
  // v first (writes vT over xT), then q (writes planar over t_v), then k (over t_q)
  kdw<<<3072, 256, 0, stream>>>(t + 2 * PART_ELEMS, wdw, bdw, 2, 1,
                                nullptr, nullptr, ws + OFF_XT);
  kdw<<<3072, 256, 0, stream>>>(t, wdw, bdw, 0, 0,
                                t + 2 * PART_ELEMS, (float*)(ws + OFF_NQ), nullptr);
  kdw<<<3072, 256, 0, stream>>>(t + PART_ELEMS, wdw, bdw, 1, 0,
                                t, (float*)(ws + OFF_NK), nullptr);
  kgram<<<256, 256, 0, stream>>>(t + 2 * PART_ELEMS, t, (float*)(ws + OFF_G));
  kattn<<<64, 256, 0, stream>>>((const float*)(ws + OFF_G), (const float*)(ws + OFF_NQ),
                                (const float*)(ws + OFF_NK), temp, wproj, ws + OFF_W2);
  kpos<<<3072, 256, 0, stream>>>(ws + OFF_XT, wpos1, wpos2, t + PART_ELEMS);
  kproj<<<3072, 256, 0, stream>>>(ws + OFF_XT, ws + OFF_W2, bproj,
                                  t + PART_ELEMS, (float*)d_out);
}

// Round 3
// 326.034 us; speedup vs baseline: 2.3603x; 1.0795x over previous
//
#include <hip/hip_runtime.h>
#include <stdint.h>
#include <stddef.h>

#define NB 8
#define CC 192
#define C3 576
#define HGT 128
#define WID 128
#define HW 16384
#define NH 8

typedef short bf16x8 __attribute__((ext_vector_type(8)));
typedef float f32x4 __attribute__((ext_vector_type(4)));

__device__ __forceinline__ unsigned short f2bf(float f) {
  unsigned int u = __float_as_uint(f);
  u += 0x7fffu + ((u >> 16) & 1u);
  return (unsigned short)(u >> 16);
}
__device__ __forceinline__ float bf2f(unsigned short h) {
  return __uint_as_float(((unsigned int)h) << 16);
}
__device__ __forceinline__ unsigned int pk2(float a, float b) {
  return (unsigned int)f2bf(a) | ((unsigned int)f2bf(b) << 16);
}
__device__ __forceinline__ void gl_lds16(const void* g, void* l) {
  __builtin_amdgcn_global_load_lds(
      (const __attribute__((address_space(1))) unsigned int*)(uintptr_t)g,
      (__attribute__((address_space(3))) unsigned int*)(uint32_t)(uintptr_t)l,
      16, 0, 0);
}
__device__ __forceinline__ int xcd_swz(int g, int n) {
  return (g & 7) * (n >> 3) + (g >> 3);
}

// ---------------- ktrans: x [b][192][HW] f32 -> xT slot-planar [b][24][HW][16B] bf16
__global__ __launch_bounds__(256) void ktrans(const float* __restrict__ x,
                                              unsigned char* __restrict__ xT) {
  __shared__ __align__(16) float lx[192 * 68];
  int wg = xcd_swz(blockIdx.x, gridDim.x);
  int pt = wg & 255, b = wg >> 8;
  int p0 = pt * 64;
  int tid = threadIdx.x;
#pragma unroll
  for (int i = 0; i < 12; ++i) {
    int f = tid + i * 256;
    int ic = f >> 4, q = f & 15;
    float4 v = *(const float4*)(x + ((size_t)(b * CC + ic)) * HW + p0 + q * 4);
    *(float4*)(lx + ic * 68 + q * 4) = v;
  }
  __syncthreads();
#pragma unroll
  for (int i = 0; i < 6; ++i) {
    int f = i * 256 + tid;          // 1536 = 24 slots * 64 px
    int s = f >> 6, p = f & 63;
    unsigned int wv[4];
#pragma unroll
    for (int j = 0; j < 4; ++j)
      wv[j] = pk2(lx[(s * 8 + 2 * j) * 68 + p], lx[(s * 8 + 2 * j + 1) * 68 + p]);
    uint4 st; st.x = wv[0]; st.y = wv[1]; st.z = wv[2]; st.w = wv[3];
    *(uint4*)(xT + (((size_t)(b * 24 + s)) * HW + p0 + p) * 16) = st;
  }
}

// ---------------- kwprep: w_qkv [576][192] f32 -> bf16 swizzled rows
__global__ void kwprep(const float* __restrict__ wq, unsigned char* __restrict__ wb) {
  int f = blockIdx.x * 256 + threadIdx.x;
  if (f >= C3 * 24) return;
  int oc = f / 24, s = f % 24;
  unsigned int wv[4];
#pragma unroll
  for (int j = 0; j < 4; ++j)
    wv[j] = pk2(wq[oc * 192 + s * 8 + 2 * j], wq[oc * 192 + s * 8 + 2 * j + 1]);
  uint4 st; st.x = wv[0]; st.y = wv[1]; st.z = wv[2]; st.w = wv[3];
  *(uint4*)(wb + (size_t)oc * 384 + ((s ^ (oc & 7)) * 16)) = st;
}

// ---------------- kconv1: pipelined 64px tiles; v -> planar, q/k -> unit-interleaved
__global__ __launch_bounds__(256) void kconv1(const unsigned char* __restrict__ xT,
                                              const unsigned char* __restrict__ wb,
                                              const float* __restrict__ bqkv,
                                              unsigned short* __restrict__ vout,
                                              unsigned char* __restrict__ qkout) {
  __shared__ __align__(16) unsigned char lds[73728]; // A dbuf 2x24576, B @49152
  int wg = xcd_swz(blockIdx.x, gridDim.x);
  int ot = wg % 9; int rest = wg / 9; int grp = rest & 63; int b = rest >> 6;
  int tid = threadIdx.x;
  const unsigned char* gB = wb + (size_t)ot * 24576;
#pragma unroll
  for (int i = 0; i < 6; ++i)
    gl_lds16(gB + i * 4096 + tid * 16, lds + 49152 + i * 4096 + tid * 16);
  const unsigned char* gA = xT + (size_t)b * 24 * HW * 16;
  int t0 = grp * 4;
  {
    int p0 = t0 * 64;
#pragma unroll
    for (int i = 0; i < 6; ++i) {
      int f = i * 256 + tid;
      gl_lds16(gA + (((size_t)(f >> 6)) * HW + p0 + (f & 63)) * 16, lds + f * 16);
    }
  }
  int lane = tid & 63, w = tid >> 6;
  int l15 = lane & 15, gq = lane >> 4;
  int pw = w * 16;
  float bias[4];
  size_t obase[4];
  int isv[4];
#pragma unroll
  for (int nf = 0; nf < 4; ++nf) {
    int oc = ot * 64 + nf * 16 + l15;
    bias[nf] = bqkv[oc];
    if (oc >= 384) {
      isv[nf] = 1;
      obase[nf] = ((size_t)(b * CC + oc - 384)) * HW * 2;
    } else {
      isv[nf] = 0;
      int part = oc >= 192 ? 1 : 0;
      int cm = oc - part * 192;
      int h = cm / 24, ch = cm % 24;
      obase[nf] = (size_t)(((part * 8 + b) * 8 + h) * 128) * 6144 + ch * 16 + (gq & 1) * 8;
    }
  }
  for (int it = 0; it < 4; ++it) {
    int tile = t0 + it;
    asm volatile("s_waitcnt vmcnt(0)" ::: "memory");
    __syncthreads();
    int nb = it & 1;
    if (it < 3) {
      int p1 = (tile + 1) * 64;
#pragma unroll
      for (int i = 0; i < 6; ++i) {
        int f = i * 256 + tid;
        gl_lds16(gA + (((size_t)(f >> 6)) * HW + p1 + (f & 63)) * 16,
                 lds + ((nb ^ 1) * 24576) + f * 16);
      }
    }
    f32x4 acc[4];
#pragma unroll
    for (int nf = 0; nf < 4; ++nf) acc[nf] = (f32x4){0.f, 0.f, 0.f, 0.f};
#pragma unroll
    for (int kk = 0; kk < 6; ++kk) {
      bf16x8 a = *(const bf16x8*)(lds + nb * 24576 + ((((kk * 4 + gq) << 6) + pw + l15) * 16));
      int cb = kk * 64 + gq * 16;
#pragma unroll
      for (int nf = 0; nf < 4; ++nf) {
        int r = nf * 16 + l15;
        bf16x8 bfr = *(const bf16x8*)(lds + 49152 + r * 384 + (cb ^ ((r & 7) << 4)));
        acc[nf] = __builtin_amdgcn_mfma_f32_16x16x32_bf16(a, bfr, acc[nf], 0, 0, 0);
      }
    }
    int p = tile * 64 + pw + gq * 4;
    int y = p >> 7, x = p & 127;
#pragma unroll
    for (int nf = 0; nf < 4; ++nf) {
      uint2 st;
      st.x = pk2(acc[nf][0] + bias[nf], acc[nf][1] + bias[nf]);
      st.y = pk2(acc[nf][2] + bias[nf], acc[nf][3] + bias[nf]);
      if (isv[nf]) {
        *(uint2*)((unsigned char*)vout + obase[nf] + (size_t)p * 2) = st;
      } else {
        *(uint2*)(qkout + obase[nf] + (size_t)y * 6144 + (x >> 3) * 384) = st;
      }
    }
  }
}

// ---------------- kqk: fused dwconv(q,k) + Gram + norms (frag-direct)
__device__ __forceinline__ void dwoct(const unsigned char* lds, int t, int r0,
                                      int xu, int ch, const float* w, float bias,
                                      float* o) {
#pragma unroll
  for (int j = 0; j < 8; ++j) o[j] = bias;
#pragma unroll
  for (int dy = 0; dy < 3; ++dy) {
    int ub = ((t * 6 + r0 + dy) * 16) * 24 + ch;
    union { bf16x8 v; unsigned short s[8]; } m;
    m.v = *(const bf16x8*)(lds + (size_t)(ub + xu * 24) * 16);
    unsigned short lft = *(const unsigned short*)(lds + (size_t)(ub + (xu > 0 ? xu - 1 : 0) * 24) * 16 + 14);
    unsigned short rgt = *(const unsigned short*)(lds + (size_t)(ub + (xu < 15 ? xu + 1 : 15) * 24) * 16);
    float vwin[10];
    vwin[0] = (xu > 0) ? bf2f(lft) : 0.f;
    vwin[9] = (xu < 15) ? bf2f(rgt) : 0.f;
#pragma unroll
    for (int j = 0; j < 8; ++j) vwin[1 + j] = bf2f(m.s[j]);
#pragma unroll
    for (int j = 0; j < 8; ++j)
      o[j] += vwin[j] * w[dy * 3] + vwin[j + 1] * w[dy * 3 + 1] + vwin[j + 2] * w[dy * 3 + 2];
  }
}

__global__ __launch_bounds__(256) void kqk(const unsigned char* __restrict__ qk,
                                           const float* __restrict__ wdw,
                                           const float* __restrict__ bdw,
                                           float* __restrict__ G,
                                           float* __restrict__ nq,
                                           float* __restrict__ nk) {
  __shared__ __align__(16) unsigned char lds[73728];
  int wg = xcd_swz(blockIdx.x, gridDim.x);
  int band = wg & 31, bh = wg >> 5;
  int h = bh & 7, b = bh >> 3;
  int y0 = band * 4;
  int tid = threadIdx.x;
  if (band == 0 || band == 31) {
#pragma unroll
    for (int i = 0; i < 18; ++i)
      *(uint4*)(lds + (i * 256 + tid) * 16) = (uint4){0, 0, 0, 0};
    __syncthreads();
  }
#pragma unroll
  for (int i = 0; i < 18; ++i) {
    int f = i * 256 + tid;
    int t = f / 2304, rem = f % 2304;
    int r = rem / 384, u = rem % 384;
    int y = y0 - 1 + r;
    if (y >= 0 && y < HGT)
      gl_lds16(qk + ((size_t)(((t * 8 + b) * 8 + h) * 128 + y)) * 6144 + u * 16,
               lds + f * 16);
  }
  asm volatile("s_waitcnt vmcnt(0)" ::: "memory");
  __syncthreads();

  int lane = tid & 63, w = tid >> 6;
  int l15 = lane & 15, gq = lane >> 4;
  int ch0 = l15;
  int ch1 = (l15 < 8) ? 16 + l15 : 23;   // clamped; garbage lands in unused acc cells
  int c0 = h * 24 + ch0, c1 = h * 24 + ch1;
  float wq0[9], wq1[9], wk0[9], wk1[9];
#pragma unroll
  for (int j = 0; j < 9; ++j) {
    wq0[j] = wdw[c0 * 9 + j];        wq1[j] = wdw[c1 * 9 + j];
    wk0[j] = wdw[(192 + c0) * 9 + j]; wk1[j] = wdw[(192 + c1) * 9 + j];
  }
  float bq0 = bdw[c0], bq1 = bdw[c1], bk0 = bdw[192 + c0], bk1 = bdw[192 + c1];

  f32x4 acc[2][2];
#pragma unroll
  for (int ct = 0; ct < 2; ++ct)
#pragma unroll
    for (int dt = 0; dt < 2; ++dt) acc[ct][dt] = (f32x4){0.f, 0.f, 0.f, 0.f};
  float nq0 = 0.f, nq1 = 0.f, nk0 = 0.f, nk1 = 0.f;

#pragma unroll
  for (int j4 = 0; j4 < 4; ++j4) {
    int kt = w * 4 + j4;
    int r0 = kt >> 2;
    int xu = (kt & 3) * 4 + gq;
    union { bf16x8 v; unsigned int u[4]; } fq0, fq1, fk0, fk1;
    {
      float o[8];
      dwoct(lds, 0, r0, xu, ch0, wq0, bq0, o);
#pragma unroll
      for (int j = 0; j < 8; ++j) nq0 += o[j] * o[j];
#pragma unroll
      for (int e = 0; e < 4; ++e) fq0.u[e] = pk2(o[2 * e], o[2 * e + 1]);
    }
    {
      float o[8];
      dwoct(lds, 0, r0, xu, ch1, wq1, bq1, o);
#pragma unroll
      for (int j = 0; j < 8; ++j) nq1 += o[j] * o[j];
#pragma unroll
      for (int e = 0; e < 4; ++e) fq1.u[e] = pk2(o[2 * e], o[2 * e + 1]);
    }
    {
      float o[8];
      dwoct(lds, 1, r0, xu, ch0, wk0, bk0, o);
#pragma unroll
      for (int j = 0; j < 8; ++j) nk0 += o[j] * o[j];
#pragma unroll
      for (int e = 0; e < 4; ++e) fk0.u[e] = pk2(o[2 * e], o[2 * e + 1]);
    }
    {
      float o[8];
      dwoct(lds, 1, r0, xu, ch1, wk1, bk1, o);
#pragma unroll
      for (int j = 0; j < 8; ++j) nk1 += o[j] * o[j];
#pragma unroll
      for (int e = 0; e < 4; ++e) fk1.u[e] = pk2(o[2 * e], o[2 * e + 1]);
    }
    acc[0][0] = __builtin_amdgcn_mfma_f32_16x16x32_bf16(fq0.v, fk0.v, acc[0][0], 0, 0, 0);
    acc[0][1] = __builtin_amdgcn_mfma_f32_16x16x32_bf16(fq0.v, fk1.v, acc[0][1], 0, 0, 0);
    acc[1][0] = __builtin_amdgcn_mfma_f32_16x16x32_bf16(fq1.v, fk0.v, acc[1][0], 0, 0, 0);
    acc[1][1] = __builtin_amdgcn_mfma_f32_16x16x32_bf16(fq1.v, fk1.v, acc[1][1], 0, 0, 0);
  }
  __syncthreads();
  float* gp = (float*)lds;
#pragma unroll
  for (int ct = 0; ct < 2; ++ct)
#pragma unroll
    for (int dt = 0; dt < 2; ++dt)
      *(f32x4*)(gp + (((w * 4 + ct * 2 + dt) * 64) + lane) * 4) = acc[ct][dt];
  nq0 += __shfl_xor(nq0, 16); nq0 += __shfl_xor(nq0, 32);
  nq1 += __shfl_xor(nq1, 16); nq1 += __shfl_xor(nq1, 32);
  nk0 += __shfl_xor(nk0, 16); nk0 += __shfl_xor(nk0, 32);
  nk1 += __shfl_xor(nk1, 16); nk1 += __shfl_xor(nk1, 32);
  int nb24 = (b * NH + h) * 24;
  if (lane < 16) {
    atomicAdd(nq + nb24 + l15, nq0);
    atomicAdd(nk + nb24 + l15, nk0);
  }
  if (lane < 8) {
    atomicAdd(nq + nb24 + 16 + l15, nq1);
    atomicAdd(nk + nb24 + 16 + l15, nk1);
  }
  __syncthreads();
  float* Gb = G + (size_t)(b * NH + h) * 576;
#pragma unroll
  for (int ii = 0; ii < 3; ++ii) {
    int f = ii * 256 + tid;
    if (f < 576) {
      int c = f / 24, d = f % 24;
      int t4 = ((c >> 4) << 1) + (d >> 4);
      int lane16 = (d & 15) + (((c & 15) >> 2) << 4);
      int reg = c & 3;
      float s = 0.f;
#pragma unroll
      for (int w4 = 0; w4 < 4; ++w4)
        s += gp[((w4 * 4 + t4) * 64 + lane16) * 4 + reg];
      atomicAdd(Gb + f, s);
    }
  }
}

// ---------------- kdwv: depthwise 3x3 on v part -> vT slot-planar
__global__ __launch_bounds__(256) void kdwv(const unsigned short* __restrict__ src,
                                            const float* __restrict__ wdw,
                                            const float* __restrict__ bdw,
                                            unsigned char* __restrict__ vT) {
  __shared__ __align__(16) unsigned int smem[8 * 721];
  int wg = xcd_swz(blockIdx.x, gridDim.x);
  int cg = wg % 24, rt = (wg / 24) & 15, b = wg / 384;
  int y0 = rt * 8, chg0 = cg * 8;
  int tid = threadIdx.x;
  for (int i = tid; i < 5768; i += 256) smem[i] = 0;
  __syncthreads();
#pragma unroll
  for (int i = 0; i < 5; ++i) {
    int f = i * 256 + tid;
    int ch = f / 160, rem = f % 160;
    int r = rem >> 4, seg = rem & 15;
    int y = y0 - 1 + r;
    if (y >= 0 && y < HGT) {
      uint4 v = *(const uint4*)(src + ((size_t)(b * CC + chg0 + ch)) * HW + y * WID + seg * 8);
      unsigned int* dp = smem + ch * 721 + r * 72 + 4 + seg * 4;
      dp[0] = v.x; dp[1] = v.y; dp[2] = v.z; dp[3] = v.w;
    }
  }
  __syncthreads();
  int ch = tid >> 5, u = tid & 31;
  int row = u >> 2, xs = (u & 3) * 32;
  int gch = 384 + chg0 + ch;
  float wv[9];
#pragma unroll
  for (int j = 0; j < 9; ++j) wv[j] = wdw[gch * 9 + j];
  float bias = bdw[gch];
  float outv[32];
  const unsigned int* tb = smem + ch * 721;
#pragma unroll
  for (int g = 0; g < 4; ++g) {
    int x0 = xs + g * 8;
    float v[3][12];
#pragma unroll
    for (int dy = 0; dy < 3; ++dy) {
      const unsigned int* rp = tb + (row + dy) * 72 + ((x0 + 6) >> 1);
#pragma unroll
      for (int m = 0; m < 6; ++m) {
        unsigned int w2 = rp[m];
        v[dy][2 * m] = bf2f((unsigned short)(w2 & 0xffff));
        v[dy][2 * m + 1] = bf2f((unsigned short)(w2 >> 16));
      }
    }
#pragma unroll
    for (int j = 0; j < 8; ++j) {
      float a = bias;
#pragma unroll
      for (int dy = 0; dy < 3; ++dy)
#pragma unroll
        for (int dx = 0; dx < 3; ++dx)
          a += v[dy][j + dx + 1] * wv[dy * 3 + dx];
      outv[g * 8 + j] = a;
    }
  }
  __syncthreads();
  unsigned short* vt = (unsigned short*)smem;   // [8][8][128] u16
#pragma unroll
  for (int g = 0; g < 4; ++g)
#pragma unroll
    for (int j = 0; j < 8; j += 2) {
      int x = xs + g * 8 + j;
      ((unsigned int*)smem)[ch * 512 + row * 64 + (x >> 1)] =
          pk2(outv[g * 8 + j], outv[g * 8 + j + 1]);
    }
  __syncthreads();
#pragma unroll
  for (int i = 0; i < 4; ++i) {
    int f = i * 256 + tid;
    int r = f >> 7, col = f & 127;
    unsigned int wvp[4];
#pragma unroll
    for (int e = 0; e < 4; ++e) {
      unsigned short a = vt[(2 * e) * 1024 + r * 128 + col];
      unsigned short bb = vt[(2 * e + 1) * 1024 + r * 128 + col];
      wvp[e] = (unsigned int)a | ((unsigned int)bb << 16);
    }
    uint4 st; st.x = wvp[0]; st.y = wvp[1]; st.z = wvp[2]; st.w = wvp[3];
    *(uint4*)(vT + (((size_t)(b * 24 + cg)) * HW + (size_t)(y0 + r) * WID + col) * 16) = st;
  }
}

// ---------------- kattn: softmax + fold w_proj -> W2[b] (bf16 swz rows)
__global__ __launch_bounds__(256) void kattn(const float* __restrict__ G,
                                             const float* __restrict__ nq,
                                             const float* __restrict__ nk,
                                             const float* __restrict__ temp,
                                             const float* __restrict__ wproj,
                                             unsigned char* __restrict__ W2) {
  __shared__ float attn[24][24];
  __shared__ float iq[24], ik[24];
  int bh = blockIdx.x;
  int h = bh & 7, b = bh >> 3;
  int tid = threadIdx.x;
  const float* Gb = G + (size_t)bh * 576;
  if (tid < 24) { float n = sqrtf(nq[bh * 24 + tid]); iq[tid] = 1.f / fmaxf(n, 1e-12f); }
  else if (tid < 48) { float n = sqrtf(nk[bh * 24 + tid - 24]); ik[tid - 24] = 1.f / fmaxf(n, 1e-12f); }
  __syncthreads();
  if (tid < 24) {
    float tmp = temp[h];
    float row[24];
    float mx = -1e30f;
#pragma unroll
    for (int d = 0; d < 24; ++d) {
      row[d] = Gb[tid * 24 + d] * iq[tid] * ik[d] * tmp;
      mx = fmaxf(mx, row[d]);
    }
    float sum = 0.f;
#pragma unroll
    for (int d = 0; d < 24; ++d) { float e = expf(row[d] - mx); row[d] = e; sum += e; }
    float inv = 1.f / sum;
#pragma unroll
    for (int d = 0; d < 24; ++d) attn[tid][d] = row[d] * inv;
  }
  __syncthreads();
  for (int i = 0; i < 18; ++i) {
    int f = tid + i * 256;
    if (f >= 4608) break;
    int oc = f / 24, d = f % 24;
    float s = 0.f;
#pragma unroll
    for (int c = 0; c < 24; ++c) s += wproj[oc * 192 + h * 24 + c] * attn[c][d];
    int gg = h * 24 + d;
    *(unsigned short*)(W2 + ((size_t)b * CC + oc) * 384 + ((gg * 2) ^ ((oc & 7) << 4))) = f2bf(s);
  }
}

// ---------------- kpos: pos = dwconv(gelu(dwconv(v,w1)),w2) ; v from vT slot-planar
__global__ __launch_bounds__(256) void kpos(const unsigned char* __restrict__ vT,
                                            const float* __restrict__ w1,
                                            const float* __restrict__ w2,
                                            unsigned short* __restrict__ pos) {
  __shared__ unsigned int vbuf[8 * 865];
  __shared__ unsigned int d1[8 * 721];
  int wg = xcd_swz(blockIdx.x, gridDim.x);
  int cg = wg % 24, rt = (wg / 24) & 15, b = wg / 384;
  int y0 = rt * 8, g0 = cg * 8;
  int tid = threadIdx.x;
  for (int i = tid; i < 6920; i += 256) vbuf[i] = 0;
  __syncthreads();
#pragma unroll
  for (int i = 0; i < 3; ++i) {
    int f = i * 256 + tid;
    int r = f >> 6, colp = f & 63;
    int y = y0 - 2 + r;
    if (y >= 0 && y < HGT) {
      const unsigned char* base = vT + (((size_t)(b * 24 + cg)) * HW + (size_t)y * WID + colp * 2) * 16;
      uint4 va = *(const uint4*)(base);
      uint4 vb2 = *(const uint4*)(base + 16);
      unsigned int la[4] = {va.x, va.y, va.z, va.w};
      unsigned int lb[4] = {vb2.x, vb2.y, vb2.z, vb2.w};
#pragma unroll
      for (int e = 0; e < 8; ++e) {
        unsigned int a16 = (la[e >> 1] >> ((e & 1) * 16)) & 0xffff;
        unsigned int b16 = (lb[e >> 1] >> ((e & 1) * 16)) & 0xffff;
        vbuf[e * 865 + r * 72 + colp + 4] = a16 | (b16 << 16);
      }
    }
  }
  __syncthreads();
  int ch = tid >> 5, u = tid & 31;
  {
    const float* wp = w1 + (g0 + ch) * 9;
    float wl[9];
#pragma unroll
    for (int j = 0; j < 9; ++j) wl[j] = wp[j];
    int x0 = u * 4;
    for (int rr = 0; rr < 10; ++rr) {
      int y = y0 - 1 + rr;
      unsigned int o0 = 0, o1 = 0;
      if (y >= 0 && y < HGT) {
        float v[3][8];
#pragma unroll
        for (int dy = 0; dy < 3; ++dy) {
          const unsigned int* rp = vbuf + ch * 865 + (rr + dy) * 72 + ((x0 + 6) >> 1);
#pragma unroll
          for (int m = 0; m < 4; ++m) {
            unsigned int w2r = rp[m];
            v[dy][2 * m] = bf2f((unsigned short)(w2r & 0xffff));
            v[dy][2 * m + 1] = bf2f((unsigned short)(w2r >> 16));
          }
        }
        float g4[4];
#pragma unroll
        for (int j = 0; j < 4; ++j) {
          float a = 0.f;
#pragma unroll
          for (int dy = 0; dy < 3; ++dy)
#pragma unroll
            for (int dx = 0; dx < 3; ++dx)
              a += v[dy][j + dx + 1] * wl[dy * 3 + dx];
          g4[j] = 0.5f * a * (1.f + erff(a * 0.70710678118f));
        }
        o0 = pk2(g4[0], g4[1]);
        o1 = pk2(g4[2], g4[3]);
      }
      unsigned int* dp = d1 + ch * 721 + rr * 72 + ((x0 + 8) >> 1);
      dp[0] = o0; dp[1] = o1;
    }
  }
  if (tid < 160) {
    int ech = tid / 20, rem = tid % 20;
    int rr = rem >> 1, side = rem & 1;
    int x = side ? 128 : -1;
    int y = y0 - 1 + rr;
    unsigned short val = 0;
    if (y >= 0 && y < HGT) {
      const float* wp = w1 + (g0 + ech) * 9;
      float a = 0.f;
      const unsigned short* vb16 = (const unsigned short*)(vbuf + ech * 865);
#pragma unroll
      for (int dy = 0; dy < 3; ++dy)
#pragma unroll
        for (int dx = 0; dx < 3; ++dx)
          a += bf2f(vb16[(rr + dy) * 144 + (x + dx + 7)]) * wp[dy * 3 + dx];
      val = f2bf(0.5f * a * (1.f + erff(a * 0.70710678118f)));
    }
    ((unsigned short*)(d1 + ech * 721))[rr * 144 + (x + 8)] = val;
  }
  __syncthreads();
  {
    const float* wp = w2 + (g0 + ch) * 9;
    float wl[9];
#pragma unroll
    for (int j = 0; j < 9; ++j) wl[j] = wp[j];
    int row = u >> 2, xs = (u & 3) * 32;
    size_t rb = ((size_t)(b * CC + g0 + ch)) * HW + (size_t)(y0 + row) * WID;
#pragma unroll
    for (int g = 0; g < 4; ++g) {
      int x0 = xs + g * 8;
      float v[3][12];
#pragma unroll
      for (int dy = 0; dy < 3; ++dy) {
        const unsigned int* rp = d1 + ch * 721 + (row + dy) * 72 + ((x0 + 6) >> 1);
#pragma unroll
        for (int m = 0; m < 6; ++m) {
          unsigned int w2r = rp[m];
          v[dy][2 * m] = bf2f((unsigned short)(w2r & 0xffff));
          v[dy][2 * m + 1] = bf2f((unsigned short)(w2r >> 16));
        }
      }
      uint4 st;
      float o[8];
#pragma unroll
      for (int j = 0; j < 8; ++j) {
        float a = 0.f;
#pragma unroll
        for (int dy = 0; dy < 3; ++dy)
#pragma unroll
          for (int dx = 0; dx < 3; ++dx)
            a += v[dy][j + dx + 1] * wl[dy * 3 + dx];
        o[j] = a;
      }
      st.x = pk2(o[0], o[1]); st.y = pk2(o[2], o[3]);
      st.z = pk2(o[4], o[5]); st.w = pk2(o[6], o[7]);
      *(uint4*)(pos + rb + x0) = st;
    }
  }
}

// ---------------- kproj: pipelined 64px tiles; out = W2.v + bproj + pos (f32)
__global__ __launch_bounds__(256) void kproj(const unsigned char* __restrict__ vT,
                                             const unsigned char* __restrict__ W2,
                                             const float* __restrict__ bproj,
                                             const unsigned short* __restrict__ pos,
                                             float* __restrict__ out) {
  __shared__ __align__(16) unsigned char lds[73728];
  int wg = xcd_swz(blockIdx.x, gridDim.x);
  int ot = wg % 3; int rest = wg / 3; int grp = rest & 63; int b = rest >> 6;
  int tid = threadIdx.x;
  const unsigned char* gB = W2 + ((size_t)(b * 192 + ot * 64)) * 384;
#pragma unroll
  for (int i = 0; i < 6; ++i)
    gl_lds16(gB + i * 4096 + tid * 16, lds + 49152 + i * 4096 + tid * 16);
  const unsigned char* gA = vT + (size_t)b * 24 * HW * 16;
  int t0 = grp * 4;
  {
    int p0 = t0 * 64;
#pragma unroll
    for (int i = 0; i < 6; ++i) {
      int f = i * 256 + tid;
      gl_lds16(gA + (((size_t)(f >> 6)) * HW + p0 + (f & 63)) * 16, lds + f * 16);
    }
  }
  int lane = tid & 63, w = tid >> 6;
  int l15 = lane & 15, gq = lane >> 4;
  int pw = w * 16;
  float bias[4];
  size_t obase[4];
#pragma unroll
  for (int nf = 0; nf < 4; ++nf) {
    int oc = ot * 64 + nf * 16 + l15;
    bias[nf] = bproj[oc];
    obase[nf] = ((size_t)(b * 192 + oc)) * HW;
  }
  for (int it = 0; it < 4; ++it) {
    int tile = t0 + it;
    asm volatile("s_waitcnt vmcnt(0)" ::: "memory");
    __syncthreads();
    int nb = it & 1;
    if (it < 3) {
      int p1 = (tile + 1) * 64;
#pragma unroll
      for (int i = 0; i < 6; ++i) {
        int f = i * 256 + tid;
        gl_lds16(gA + (((size_t)(f >> 6)) * HW + p1 + (f & 63)) * 16,
                 lds + ((nb ^ 1) * 24576) + f * 16);
      }
    }
    f32x4 acc[4];
#pragma unroll
    for (int nf = 0; nf < 4; ++nf) acc[nf] = (f32x4){0.f, 0.f, 0.f, 0.f};
#pragma unroll
    for (int kk = 0; kk < 6; ++kk) {
      bf16x8 a = *(const bf16x8*)(lds + nb * 24576 + ((((kk * 4 + gq) << 6) + pw + l15) * 16));
      int cb = kk * 64 + gq * 16;
#pragma unroll
      for (int nf = 0; nf < 4; ++nf) {
        int r = nf * 16 + l15;
        bf16x8 bfr = *(const bf16x8*)(lds + 49152 + r * 384 + (cb ^ ((r & 7) << 4)));
        acc[nf] = __builtin_amdgcn_mfma_f32_16x16x32_bf16(a, bfr, acc[nf], 0, 0, 0);
      }
    }
    int p = tile * 64 + pw + gq * 4;
#pragma unroll
    for (int nf = 0; nf < 4; ++nf) {
      uint2 pv = *(const uint2*)(pos + obase[nf] + p);
      float4 o;
      o.x = acc[nf][0] + bias[nf] + bf2f((unsigned short)(pv.x & 0xffff));
      o.y = acc[nf][1] + bias[nf] + bf2f((unsigned short)(pv.x >> 16));
      o.z = acc[nf][2] + bias[nf] + bf2f((unsigned short)(pv.y & 0xffff));
      o.w = acc[nf][3] + bias[nf] + bf2f((unsigned short)(pv.y >> 16));
      *(float4*)(out + obase[nf] + p) = o;
    }
  }
}

// ---------------- workspace layout ----------------
#define OFF_W   ((size_t)0)                    // 221184
#define OFF_G   ((size_t)221184)               // 147456
#define OFF_NQ  ((size_t)368640)               // 6144
#define OFF_NK  ((size_t)374784)               // 6144
#define OFF_W2  ((size_t)380928)               // 589824
#define OFF_QK  ((size_t)970752)               // 100663296 : qk unit-interleaved; later pos
#define OFF_V   ((size_t)101634048)            // 50331648  : v planar
#define OFF_XT  ((size_t)151965696)            // 50331648  : xT; later vT

extern "C" void kernel_launch(void* const* d_in, const int* in_sizes, int n_in,
                              void* d_out, int out_size, void* d_ws, size_t ws_size,
                              hipStream_t stream) {
  const float* x     = (const float*)d_in[0];
  const float* wqkv  = (const float*)d_in[1];
  const float* bqkv  = (const float*)d_in[2];
  const float* wdw   = (const float*)d_in[3];
  const float* bdw   = (const float*)d_in[4];
  const float* wproj = (const float*)d_in[5];
  const float* bproj = (const float*)d_in[6];
  const float* wpos1 = (const float*)d_in[7];
  const float* wpos2 = (const float*)d_in[8];
  const float* temp  = (const float*)d_in[9];
  unsigned char* ws = (unsigned char*)d_ws;

  hipMemsetAsync(ws + OFF_G, 0, 147456 + 6144 + 6144, stream);
  kwprep<<<54, 256, 0, stream>>>(wqkv, ws + OFF_W);
  ktrans<<<2048, 256, 0, stream>>>(x, ws + OFF_XT);
  kconv1<<<4608, 256, 0, stream>>>(ws + OFF_XT, ws + OFF_W, bqkv,
                                   (unsigned short*)(ws + OFF_V), ws + OFF_QK);
  kqk<<<2048, 256, 0, stream>>>(ws + OFF_QK, wdw, bdw, (float*)(ws + OFF_G),
                                (float*)(ws + OFF_NQ), (float*)(ws + OFF_NK));
  kdwv<<<3072, 256, 0, stream>>>((const unsigned short*)(ws + OFF_V), wdw, bdw,
                                 ws + OFF_XT);
  kattn<<<64, 256, 0, stream>>>((const float*)(ws + OFF_G), (const float*)(ws + OFF_NQ),
                                (const float*)(ws + OFF_NK), temp, wproj, ws + OFF_W2);
  kpos<<<3072, 256, 0, stream>>>(ws + OFF_XT, wpos1, wpos2,
                                 (unsigned short*)(ws + OFF_QK));
  kproj<<<1536, 256, 0, stream>>>(ws + OFF_XT, ws + OFF_W2, bproj,
                                  (const unsigned short*)(ws + OFF_QK), (float*)d_out);
}